// Round 2
// baseline (168.760 us; speedup 1.0000x reference)
//
#include <hip/hip_runtime.h>

#define N_NODES 100000
#define DEG 16
#define D_FEAT 64
// 16 lanes cooperate on one row; each lane owns one float4 (16B) of the 256B row.

__global__ void spmm_hop_kernel(
    const float4* __restrict__ x4,      // [N_NODES * 16] float4
    const float*  __restrict__ values,  // [N_NODES * DEG]
    const int*    __restrict__ indices, // [N_NODES * DEG]
    float4*       __restrict__ out4)    // [N_NODES * 16] float4
{
    const int tid  = blockIdx.x * blockDim.x + threadIdx.x;
    const int row  = tid >> 4;
    const int lane = tid & 15;
    if (row >= N_NODES) return;

    // One coalesced load per lane instead of 16 broadcast loads per lane:
    // lane j holds edge j's (index, value) for this row.
    const int   my_idx = indices[row * DEG + lane];
    const float my_val = values[row * DEG + lane];

    // Issue ALL 16 gathers before any use -> 16 loads in flight per thread.
    float4 xv[DEG];
    #pragma unroll
    for (int j = 0; j < DEG; ++j) {
        const int idx = __shfl(my_idx, j, 16);            // broadcast within 16-lane group
        xv[j] = x4[(size_t)idx * 16 + lane];              // 256B coalesced row gather
    }

    float4 acc = make_float4(0.f, 0.f, 0.f, 0.f);
    #pragma unroll
    for (int j = 0; j < DEG; ++j) {
        const float v = __shfl(my_val, j, 16);
        acc.x += v * xv[j].x;
        acc.y += v * xv[j].y;
        acc.z += v * xv[j].z;
        acc.w += v * xv[j].w;
    }
    out4[(size_t)row * 16 + lane] = acc;
}

extern "C" void kernel_launch(void* const* d_in, const int* in_sizes, int n_in,
                              void* d_out, int out_size, void* d_ws, size_t ws_size,
                              hipStream_t stream) {
    const float* x       = (const float*)d_in[0];  // [N_NODES, 64] f32
    const float* values  = (const float*)d_in[1];  // [N_EDGES] f32
    // d_in[2] = indptr (degenerate fixed-degree CSR) — unused
    const int*   indices = (const int*)d_in[3];    // [N_EDGES] int32

    float* out = (float*)d_out;
    float* ws  = (float*)d_ws;

    const int threads = N_NODES * 16;
    const int block   = 256;
    const int grid    = (threads + block - 1) / block;

    spmm_hop_kernel<<<grid, block, 0, stream>>>((const float4*)x,  values, indices, (float4*)out);
    spmm_hop_kernel<<<grid, block, 0, stream>>>((const float4*)out, values, indices, (float4*)ws);
    spmm_hop_kernel<<<grid, block, 0, stream>>>((const float4*)ws,  values, indices, (float4*)out);
}